// Round 1
// baseline (152.338 us; speedup 1.0000x reference)
//
#include <hip/hip_runtime.h>
#include <math.h>

#define HW 262144   // 512*512 elements per batch
#define BPB 32      // blocks per batch
#define CHUNK 8192  // elements per block (HW / BPB)

// Monotonic unsigned mapping of float bits: preserves ordering for all
// finite floats (negatives flipped, positives offset).
__device__ __forceinline__ unsigned int fmono(float f) {
    unsigned int u = __float_as_uint(f);
    return (u & 0x80000000u) ? ~u : (u | 0x80000000u);
}

__global__ __launch_bounds__(256) void reduce_kernel(
    const float* __restrict__ pred, const float* __restrict__ label,
    unsigned long long* __restrict__ pp, unsigned long long* __restrict__ lp,
    float* __restrict__ mse)
{
    const int bi = blockIdx.x;
    const int b = bi >> 5;          // batch
    const int chunk = bi & (BPB - 1);
    const float4* p4 = (const float4*)(pred + (size_t)b * HW) + (size_t)chunk * (CHUNK / 4);
    const float4* l4 = (const float4*)(label + (size_t)b * HW) + (size_t)chunk * (CHUNK / 4);
    const int t = threadIdx.x;

    float sumsq = 0.0f;
    float pmax = -INFINITY, lmax = -INFINITY;
    unsigned int pidx = 0, lidx = 0;
    const unsigned int base = (unsigned int)chunk * CHUNK;

#pragma unroll
    for (int i = 0; i < 8; ++i) {
        const int v = i * 256 + t;          // float4 index within chunk
        const float4 p = p4[v];
        const float4 l = l4[v];
        const unsigned int e = base + (unsigned int)v * 4;  // element index in batch
        float d;
        d = p.x - l.x; sumsq += d * d;
        d = p.y - l.y; sumsq += d * d;
        d = p.z - l.z; sumsq += d * d;
        d = p.w - l.w; sumsq += d * d;
        // strict > keeps the first (lowest-index) occurrence within a thread
        if (p.x > pmax) { pmax = p.x; pidx = e;     }
        if (p.y > pmax) { pmax = p.y; pidx = e + 1; }
        if (p.z > pmax) { pmax = p.z; pidx = e + 2; }
        if (p.w > pmax) { pmax = p.w; pidx = e + 3; }
        if (l.x > lmax) { lmax = l.x; lidx = e;     }
        if (l.y > lmax) { lmax = l.y; lidx = e + 1; }
        if (l.z > lmax) { lmax = l.z; lidx = e + 3 - 1; }
        if (l.w > lmax) { lmax = l.w; lidx = e + 3; }
    }

    // pack: high 32 = monotonic value bits, low 32 = ~index so that on value
    // tie the LOWER index wins under unsigned max (matches jnp.argmax).
    unsigned long long ppk = ((unsigned long long)fmono(pmax) << 32) | (unsigned long long)(0xFFFFFFFFu - pidx);
    unsigned long long lpk = ((unsigned long long)fmono(lmax) << 32) | (unsigned long long)(0xFFFFFFFFu - lidx);

    // wave(64) shuffle reduction
    for (int off = 32; off > 0; off >>= 1) {
        sumsq += __shfl_down(sumsq, off);
        unsigned long long o;
        o = __shfl_down(ppk, off); if (o > ppk) ppk = o;
        o = __shfl_down(lpk, off); if (o > lpk) lpk = o;
    }

    __shared__ float s_sum[4];
    __shared__ unsigned long long s_pp[4], s_lp[4];
    const int wave = t >> 6, lane = t & 63;
    if (lane == 0) { s_sum[wave] = sumsq; s_pp[wave] = ppk; s_lp[wave] = lpk; }
    __syncthreads();
    if (t == 0) {
        float s = s_sum[0] + s_sum[1] + s_sum[2] + s_sum[3];
        unsigned long long P = s_pp[0], L = s_lp[0];
        #pragma unroll
        for (int i = 1; i < 4; ++i) {
            if (s_pp[i] > P) P = s_pp[i];
            if (s_lp[i] > L) L = s_lp[i];
        }
        atomicAdd(mse, s);
        atomicMax(&pp[b], P);
        atomicMax(&lp[b], L);
    }
}

__global__ void finalize_kernel(const unsigned long long* __restrict__ pp,
                                const unsigned long long* __restrict__ lp,
                                const float* __restrict__ mse,
                                float* __restrict__ out)
{
    const int i = threadIdx.x;  // 0..63, one lane per batch
    const unsigned int ip = 0xFFFFFFFFu - (unsigned int)(pp[i] & 0xFFFFFFFFull);
    const unsigned int il = 0xFFFFFFFFu - (unsigned int)(lp[i] & 0xFFFFFFFFull);
    const float rp = (float)(ip >> 9), cp = (float)(ip & 511u);
    const float rl = (float)(il >> 9), cl = (float)(il & 511u);
    float d = (rp - rl) * (rp - rl) + (cp - cl) * (cp - cl);
    for (int off = 32; off > 0; off >>= 1) d += __shfl_down(d, off);
    if (i == 0) {
        const float m = *mse;
        const float alpha = (d != 0.0f) ? (m / d) : 1.0f;
        out[0] = (m + 0.25f * alpha * d) / 64.0f;
    }
}

extern "C" void kernel_launch(void* const* d_in, const int* in_sizes, int n_in,
                              void* d_out, int out_size, void* d_ws, size_t ws_size,
                              hipStream_t stream) {
    const float* pred  = (const float*)d_in[0];
    const float* label = (const float*)d_in[1];
    float* out = (float*)d_out;

    unsigned long long* pp = (unsigned long long*)d_ws;   // 64 packed pred argmax
    unsigned long long* lp = pp + 64;                     // 64 packed label argmax
    float* mse = (float*)(lp + 64);                       // 1 float mse accumulator

    // ws is poisoned 0xAA before every launch; zero the part we use.
    hipMemsetAsync(d_ws, 0, 2 * 64 * sizeof(unsigned long long) + sizeof(float), stream);

    reduce_kernel<<<dim3(64 * BPB), dim3(256), 0, stream>>>(pred, label, pp, lp, mse);
    finalize_kernel<<<dim3(1), dim3(64), 0, stream>>>(pp, lp, mse, out);
}